// Round 19
// baseline (83.555 us; speedup 1.0000x reference)
//
#include <hip/hip_runtime.h>
#include <hip/hip_bf16.h>

// MaskedAttention: out = softmax(tril(q k^T)) v, q/k/v = x @ W{q,k,v}
// B=8 T=2048 D=1024 H=64, fp32 in/out, no 1/sqrt(H) scaling.
//
// Precision plan: q,k projections and QK^T use hi/lo bf16 splitting
// (3-MFMA "bf16x3") so logits are ~fp32-accurate; V/P plain bf16.

typedef __bf16 bf16x8 __attribute__((ext_vector_type(8)));
typedef float f32x4 __attribute__((ext_vector_type(4)));

#define MFMA16(a, b, c) __builtin_amdgcn_mfma_f32_16x16x32_bf16((a), (b), (c), 0, 0, 0)
#define SB0() __builtin_amdgcn_sched_barrier(0)
#define WAITV_(N) asm volatile("s_waitcnt vmcnt(" #N ")" ::: "memory")
#define WAITV(N) WAITV_(N)

static constexpr int BB = 8;
static constexpr int TT = 2048;
static constexpr int DD = 1024;
static constexpr int HH = 64;
static constexpr int NROW = BB * TT;       // 16384
// WC slab: [4 colgroups][16 K-16ths][40 rows = k8l*5+frag][16 cols][8 bf16]
// frag: 0=q_hi 1=q_lo 2=k_hi 3=k_lo 4=v_hi. 10KB per (cg,16th) slice.
static constexpr int WSLICE_S = 40 * 128;  // 5120 bf16 per (cg,16th)

// pack two floats to one u32 of 2 bf16 (lo, hi)
__device__ __forceinline__ unsigned pk2(float a, float b) {
  union { __bf16 h[2]; unsigned u; } r;
  r.h[0] = (__bf16)a;
  r.h[1] = (__bf16)b;
  return r.u;
}

// ---------------------------------------------------------------- W prep ---
// W [1024][64] fp32 -> WC slab (see above). Linear in (row,col).
__global__ __launch_bounds__(256) void wprep_kernel(
    const float* __restrict__ Wq, const float* __restrict__ Wk,
    const float* __restrict__ Wv, __bf16* __restrict__ WC) {
  int tid = blockIdx.x * 256 + threadIdx.x;
  if (tid >= 64 * 128) return;
  int col = tid >> 7;
  int k8 = tid & 127;
  const int g = col >> 4, c = col & 15;
  const int f = k8 >> 3, k8l = k8 & 7;  // sixteenth, local k8
  bf16x8 q_h, q_l, k_h, k_l, v_h;
#pragma unroll
  for (int j = 0; j < 8; ++j) {
    const int k = k8 * 8 + j;
    float qv = Wq[k * 64 + col];
    float kv = Wk[k * 64 + col];
    float vv = Wv[k * 64 + col];
    __bf16 qhi = (__bf16)qv;
    __bf16 khi = (__bf16)kv;
    q_h[j] = qhi;
    q_l[j] = (__bf16)(qv - (float)qhi);
    k_h[j] = khi;
    k_l[j] = (__bf16)(kv - (float)khi);
    v_h[j] = (__bf16)vv;
  }
  __bf16* base = WC + (size_t)(g * 16 + f) * WSLICE_S +
                 (size_t)(k8l * 5) * 128 + c * 8;
  *(bf16x8*)(base) = q_h;            // row k8l*5+0
  *(bf16x8*)(base + 128) = q_l;      // row k8l*5+1
  *(bf16x8*)(base + 256) = k_h;      // row k8l*5+2
  *(bf16x8*)(base + 384) = k_l;      // row k8l*5+3
  *(bf16x8*)(base + 512) = v_h;      // row k8l*5+4
}

// ------------------------------------------------------------ projection ---
// Block = 512 threads (8 waves): 128 rows x ONE 16-col group, BARRIER-FREE
// main loop. R17: lock-step barriers were the wall (no pipe >40%). R18's
// per-wave-X + shared-W-LDS raced (mixed role-dependent vmcnt FIFO).
// Now: (a) X per-wave private 3-slot LDS ring (2KB/slot), own gload_lds,
// own counted vmcnt -- slot reuse safe (lgkmcnt-complete ds_read precedes
// the overwriting DMA's issue). (b) W NOT staged: each lane plain-loads
// its 5 frags from WC per step; all 8 waves read the SAME 5KB -> L1 serves
// 7/8, L2 traffic unchanged vs LDS staging; compiler auto-waits W uses.
// Every wave's FIFO is identical: [W(s)x5, X(s+2)x2] -> WAITV(2) steady,
// WAITV(0) last two steps. ZERO barriers between steps; waves drift.
// X swizzle (rule #21 both-sides): slot c holds logical chunk c^(r&7);
// read chunk (lg*2+j)^(lr&7); source pre-swizzle (l&7)^((l>>3)&7).
// LDS 48KB. Grid 512: rg=bid&127, cg=bid>>7 -> same-x blocks on one XCD.
__global__ __launch_bounds__(512, 4) void proj_kernel(
    const float* __restrict__ x, const __bf16* __restrict__ WC,
    __bf16* __restrict__ qh, __bf16* __restrict__ ql,
    __bf16* __restrict__ kh, __bf16* __restrict__ kl,
    __bf16* __restrict__ vt) {
  __shared__ char Xlds[8 * 3 * 2048] __attribute__((aligned(16)));  // 48 KB
  const int tid = threadIdx.x;
  const int w = tid >> 6, l = tid & 63;
  const int lr = l & 15, lg = l >> 4;
  const int rg = blockIdx.x & 127, cg = blockIdx.x >> 7;
  const int r0 = rg * 128 + w * 16;

  f32x4 aq = {0.f, 0.f, 0.f, 0.f};
  f32x4 ak = {0.f, 0.f, 0.f, 0.f};
  f32x4 av = {0.f, 0.f, 0.f, 0.f};

  // per-lane W base: cg slab + frag-row (5*lg) + col lr. Step s adds
  // sixteenth (s>>1)*WSLICE_S + half (s&1)*2560 (= (s&1)*4 k8-units * 5*128).
  const __bf16* wbase =
      WC + (size_t)cg * 16 * WSLICE_S + (size_t)(5 * lg) * 128 + lr * 8;

#define STAGEX(SLOT, KGLOB)                                             \
  do {                                                                  \
    _Pragma("unroll") for (int i_ = 0; i_ < 2; ++i_) {                  \
      const float* xs_ = x +                                            \
          (size_t)(rg * 128 + w * 16 + i_ * 8 + (l >> 3)) * 1024 +      \
          (KGLOB) + (((l & 7) ^ ((l >> 3) & 7)) << 2);                  \
      __builtin_amdgcn_global_load_lds(                                 \
          (const __attribute__((address_space(1))) unsigned int*)xs_,   \
          (__attribute__((address_space(3))) unsigned int*)             \
              (Xlds + w * 6144 + (SLOT) * 2048 + i_ * 1024),            \
          16, 0, 0);                                                    \
    }                                                                   \
  } while (0)

  // One step: W(s) plain loads -> issue X(s+2) -> counted wait -> compute.
#define STEP(SS)                                                        \
  do {                                                                  \
    const __bf16* wp_ = wbase + (size_t)((SS) >> 1) * WSLICE_S +        \
                        ((SS)&1) * 2560;                                \
    bf16x8 f0 = *(const bf16x8*)(wp_);                                  \
    bf16x8 f1 = *(const bf16x8*)(wp_ + 128);                            \
    bf16x8 f2 = *(const bf16x8*)(wp_ + 256);                            \
    bf16x8 f3 = *(const bf16x8*)(wp_ + 384);                            \
    bf16x8 f4 = *(const bf16x8*)(wp_ + 512);                            \
    if ((SS) + 2 < 32) STAGEX(((SS) + 2) % 3, ((SS) + 2) * 32);         \
    if ((SS) >= 30) { WAITV(0); } else { WAITV(2); }                    \
    SB0();                                                              \
    const char* xb_ = Xlds + w * 6144 + ((SS) % 3) * 2048 + lr * 128;   \
    const float4 xA = *(const float4*)(xb_ + (((lg * 2) ^ (lr & 7)) << 4)); \
    const float4 xB = *(const float4*)(xb_ + (((lg * 2 + 1) ^ (lr & 7)) << 4)); \
    float xs[8] = {xA.x, xA.y, xA.z, xA.w, xB.x, xB.y, xB.z, xB.w};     \
    bf16x8 ah, al;                                                      \
    _Pragma("unroll") for (int j = 0; j < 8; ++j) {                     \
      __bf16 hv = (__bf16)xs[j];                                        \
      ah[j] = hv;                                                       \
      al[j] = (__bf16)(xs[j] - (float)hv);                              \
    }                                                                   \
    aq = MFMA16(ah, f0, aq);                                            \
    aq = MFMA16(ah, f1, aq);                                            \
    aq = MFMA16(al, f0, aq);                                            \
    ak = MFMA16(ah, f2, ak);                                            \
    ak = MFMA16(ah, f3, ak);                                            \
    ak = MFMA16(al, f2, ak);                                            \
    av = MFMA16(ah, f4, av);                                            \
  } while (0)

  // prologue: first two X chunks in flight
  STAGEX(0, 0);
  STAGEX(1, 32);

  STEP(0);  STEP(1);  STEP(2);  STEP(3);
  STEP(4);  STEP(5);  STEP(6);  STEP(7);
  STEP(8);  STEP(9);  STEP(10); STEP(11);
  STEP(12); STEP(13); STEP(14); STEP(15);
  STEP(16); STEP(17); STEP(18); STEP(19);
  STEP(20); STEP(21); STEP(22); STEP(23);
  STEP(24); STEP(25); STEP(26); STEP(27);
  STEP(28); STEP(29); STEP(30); STEP(31);

#undef STEP
#undef STAGEX

#pragma unroll
  for (int i = 0; i < 4; ++i) {
    const int row = r0 + lg * 4 + i;  // C-layout: row=(lane>>4)*4+reg
    const int col = cg * 16 + lr;     //           col=lane&15
    const size_t oq = (size_t)row * 64 + col;
    float qv = aq[i];
    __bf16 qhi = (__bf16)qv;
    qh[oq] = qhi;
    ql[oq] = (__bf16)(qv - (float)qhi);
    float kv = ak[i];
    __bf16 khi = (__bf16)kv;
    kh[oq] = khi;
    kl[oq] = (__bf16)(kv - (float)khi);
    const int bb = row >> 11, tt = row & 2047;
    vt[((size_t)bb * 64 + col) * 2048 + tt] = (__bf16)av[i];
  }
}

// -------------------------------------------------------------- attention ---
// Split-K flash, 4-wave blocks, K STAGED THROUGH LDS (R12: 63 -> ~32us).
// 128-key supersteps; all 256 threads DMA kh+kl (32KB) to LDS with XOR-
// pre-swizzled source (rule #21); ONE vmcnt drain per superstep; V (4
// loads, 16 reg) issued before the drain so its latency hides under it.
// K-LDS buffer aliased with the post-loop merge buffer: LDS 33.5KB ->
// 4 blocks/CU, all 1024 blocks resident, b=bid&7 XCD affinity preserved.
__global__ __launch_bounds__(256, 4) void attn_kernel(
    const __bf16* __restrict__ qh, const __bf16* __restrict__ ql,
    const __bf16* __restrict__ kh, const __bf16* __restrict__ kl,
    const __bf16* __restrict__ vt, float* __restrict__ out) {
  __shared__ char BUF[32768] __attribute__((aligned(16)));  // K stage / merge
  __shared__ float Sm[4][16];       // per-wave row maxes
  __shared__ float Sl[4][16];       // per-wave row sums
  __shared__ float Dinv[16];        // 1/denom per row
  const int w = threadIdx.x >> 6, l = threadIdx.x & 63;
  const int lr = l & 15, lg = l >> 4;
  const int b = blockIdx.x & 7;            // XCD affinity: batch -> XCD
  const int qt = 127 - (blockIdx.x >> 3);  // heavy tiles first
  const int q0 = qt * 16;
  const float NEG = -__builtin_inff();

  // Q fragments (B-operand of the swapped QK^T)
  const size_t qb = ((size_t)b * TT + q0 + lr) * 64 + lg * 8;
  const bf16x8 fqh0 = *(const bf16x8*)(qh + qb);
  const bf16x8 fqh1 = *(const bf16x8*)(qh + qb + 32);
  const bf16x8 fql0 = *(const bf16x8*)(ql + qb);
  const bf16x8 fql1 = *(const bf16x8*)(ql + qb + 32);

  f32x4 o0 = {0.f, 0.f, 0.f, 0.f}, o1 = o0, o2 = o0, o3 = o0;
  float m_s = NEG;   // running max for q-row (q0+lr), shared by 4 lg-lanes
  float su_s = 0.f;  // partial denom for q-row (this lane's keys only)
  const int nkt = (q0 + 47) >> 5;    // ceil((q0+16)/32)
  const int nsup = (nkt + 3) >> 2;   // 128-key supersteps

  bf16x8 v0, v1, v2, v3;
  f32x4 sa, sb;

  // LDS element offset for logical (row r, colgroup c) with XOR swizzle.
  // kh rows at bf16 index 0.., kl at +8192 (byte 16384).
#define KOFF(R, C) ((R) * 64 + ((((C) ^ ((R)&7))) * 8))

  // Stage kh+kl for keys [sup*128, +128) into BUF. Dest is linear
  // (slot = w*1024 + i*4096 + lane*16 -> row w*8+i*32+(l>>3), cg l&7);
  // source colgroup pre-swizzled: (l&7)^(l>>3) since row&7 == l>>3.
#define STAGE(SUP)                                                         \
  do {                                                                     \
    const size_t kbase_ = ((size_t)b * TT + (size_t)(SUP) * 128) * 64;     \
    const size_t rowco_ = (size_t)(w * 8 + (l >> 3)) * 64 +                \
                          (size_t)(((l & 7) ^ (l >> 3)) * 8);              \
    const __bf16* srck_ = kh + kbase_ + rowco_;                            \
    const __bf16* srcl_ = kl + kbase_ + rowco_;                            \
    _Pragma("unroll") for (int i_ = 0; i_ < 4; ++i_) {                     \
      __builtin_amdgcn_global_load_lds(                                    \
          (const __attribute__((address_space(1))) unsigned int*)(srck_ + i_ * 2048), \
          (__attribute__((address_space(3))) unsigned int*)(BUF + w * 1024 + i_ * 4096), \
          16, 0, 0);                                                       \
    }                                                                      \
    _Pragma("unroll") for (int i_ = 0; i_ < 4; ++i_) {                     \
      __builtin_amdgcn_global_load_lds(                                    \
          (const __attribute__((address_space(1))) unsigned int*)(srcl_ + i_ * 2048), \
          (__attribute__((address_space(3))) unsigned int*)(BUF + 16384 + w * 1024 + i_ * 4096), \
          16, 0, 0);                                                       \
    }                                                                      \
  } while (0)

#define LDV(KT)                                                        \
  do {                                                                 \
    const size_t vb_ =                                                 \
        ((size_t)b * 64 + lr) * 2048 + (KT) * 32 + lg * 8;             \
    v0 = *(const bf16x8*)(vt + vb_);                                   \
    v1 = *(const bf16x8*)(vt + vb_ + (size_t)16 * 2048);               \
    v2 = *(const bf16x8*)(vt + vb_ + (size_t)32 * 2048);               \
    v3 = *(const bf16x8*)(vt + vb_ + (size_t)48 * 2048);               \
  } while (0)

  // QK^T from LDS K (wave w's 32-key tile = buffer rows w*32..w*32+31).
#define QKM(KT)                                                        \
  do {                                                                 \
    const int j0_ = (KT) * 32;                                         \
    const int rA_ = w * 32 + lr, rB_ = rA_ + 16;                       \
    const __bf16* Kb_ = (const __bf16*)BUF;                            \
    const bf16x8 fk0 = *(const bf16x8*)(Kb_ + KOFF(rA_, lg));          \
    const bf16x8 fk1 = *(const bf16x8*)(Kb_ + KOFF(rA_, 4 + lg));      \
    const bf16x8 fl0 = *(const bf16x8*)(Kb_ + 8192 + KOFF(rA_, lg));   \
    const bf16x8 fl1 = *(const bf16x8*)(Kb_ + 8192 + KOFF(rA_, 4 + lg)); \
    const bf16x8 gk0 = *(const bf16x8*)(Kb_ + KOFF(rB_, lg));          \
    const bf16x8 gk1 = *(const bf16x8*)(Kb_ + KOFF(rB_, 4 + lg));      \
    const bf16x8 gl0 = *(const bf16x8*)(Kb_ + 8192 + KOFF(rB_, lg));   \
    const bf16x8 gl1 = *(const bf16x8*)(Kb_ + 8192 + KOFF(rB_, 4 + lg)); \
    const f32x4 z_ = {0.f, 0.f, 0.f, 0.f};                             \
    {                                                                  \
      f32x4 c0_ = MFMA16(fk1, fqh1, MFMA16(fk0, fqh0, z_));            \
      f32x4 c1_ = MFMA16(fk1, fql1, MFMA16(fk0, fql0, z_));            \
      f32x4 c2_ = MFMA16(fl1, fqh1, MFMA16(fl0, fqh0, z_));            \
      sa = c0_ + c1_ + c2_;                                            \
    }                                                                  \
    sb = (f32x4){NEG, NEG, NEG, NEG};                                  \
    if ((j0_ + 16) <= (q0 + 15)) {                                     \
      f32x4 c0_ = MFMA16(gk1, fqh1, MFMA16(gk0, fqh0, z_));            \
      f32x4 c1_ = MFMA16(gk1, fql1, MFMA16(gk0, fql0, z_));            \
      f32x4 c2_ = MFMA16(gl1, fqh1, MFMA16(gl0, fqh0, z_));            \
      sb = c0_ + c1_ + c2_;                                            \
    }                                                                  \
    _Pragma("unroll") for (int i = 0; i < 4; ++i) {                    \
      if (j0_ + lg * 4 + i > q0 + lr) sa[i] = NEG;                     \
      if (j0_ + 16 + lg * 4 + i > q0 + lr) sb[i] = NEG;                \
    }                                                                  \
  } while (0)

#define SPV()                                                          \
  do {                                                                 \
    float t_ = fmaxf(fmaxf(fmaxf(sa[0], sa[1]), fmaxf(sa[2], sa[3])),  \
                     fmaxf(fmaxf(sb[0], sb[1]), fmaxf(sb[2], sb[3]))); \
    t_ = fmaxf(t_, __shfl_xor(t_, 16, 64));                            \
    t_ = fmaxf(t_, __shfl_xor(t_, 32, 64));                            \
    const float mn_ = fmaxf(m_s, t_);                                  \
    const float sc_ = __expf(m_s - mn_);                               \
    m_s = mn_;                                                         \
    const float pa0_ = __expf(sa[0] - mn_), pa1_ = __expf(sa[1] - mn_);\
    const float pa2_ = __expf(sa[2] - mn_), pa3_ = __expf(sa[3] - mn_);\
    const float pb0_ = __expf(sb[0] - mn_), pb1_ = __expf(sb[1] - mn_);\
    const float pb2_ = __expf(sb[2] - mn_), pb3_ = __expf(sb[3] - mn_);\
    su_s = su_s * sc_ + ((pa0_ + pa1_) + (pa2_ + pa3_)) +              \
           ((pb0_ + pb1_) + (pb2_ + pb3_));                            \
    _Pragma("unroll") for (int i = 0; i < 4; ++i) {                    \
      const float scr_ = __shfl(sc_, lg * 4 + i, 64);                  \
      o0[i] *= scr_; o1[i] *= scr_; o2[i] *= scr_; o3[i] *= scr_;      \
    }                                                                  \
    const unsigned x0_ = pk2(pa0_, pa1_), x1_ = pk2(pa2_, pa3_);       \
    const unsigned y0_ = pk2(pb0_, pb1_), y1_ = pk2(pb2_, pb3_);       \
    const bool e_ = (lg & 1) != 0;                                     \
    const unsigned s0_ = e_ ? x0_ : y0_, s1_ = e_ ? x1_ : y1_;         \
    const unsigned r0_ = __shfl_xor(s0_, 16, 64);                      \
    const unsigned r1_ = __shfl_xor(s1_, 16, 64);                      \
    unsigned z0_ = e_ ? r0_ : x0_;                                     \
    unsigned z1_ = e_ ? r1_ : x1_;                                     \
    unsigned z2_ = e_ ? y0_ : r0_;                                     \
    unsigned z3_ = e_ ? y1_ : r1_;                                     \
    const unsigned u0_ = __shfl_xor(z0_, 48, 64);                      \
    const unsigned u1_ = __shfl_xor(z1_, 48, 64);                      \
    const unsigned u2_ = __shfl_xor(z2_, 48, 64);                      \
    const unsigned u3_ = __shfl_xor(z3_, 48, 64);                      \
    const bool sw_ = (lg == 1) || (lg == 2);                           \
    z0_ = sw_ ? u0_ : z0_; z1_ = sw_ ? u1_ : z1_;                      \
    z2_ = sw_ ? u2_ : z2_; z3_ = sw_ ? u3_ : z3_;                      \
    union { unsigned u[4]; bf16x8 v; } pfu_;                           \
    pfu_.u[0] = z0_; pfu_.u[1] = z1_;                                  \
    pfu_.u[2] = z2_; pfu_.u[3] = z3_;                                  \
    const bf16x8 pf_ = pfu_.v;                                         \
    o0 = MFMA16(pf_, v0, o0);                                          \
    o1 = MFMA16(pf_, v1, o1);                                          \
    o2 = MFMA16(pf_, v2, o2);                                          \
    o3 = MFMA16(pf_, v3, o3);                                          \
  } while (0)

#pragma unroll 1
  for (int sup = 0; sup < nsup; ++sup) {
    if (sup) __syncthreads();        // waves done reading previous K tiles
    STAGE(sup);                      // DMA kh+kl (32KB) -> BUF
    const int kt = sup * 4 + w;      // this wave's tile in the superstep
    const bool act = kt < nkt;       // wave-uniform
    if (act) LDV(kt);                // V in regs; hidden under the drain
    __syncthreads();                 // vmcnt(0) drain: DMA + V complete
    if (act) {
      QKM(kt);                       // K frags from LDS (swizzled ds_read)
      SPV();
    }
  }
#undef KOFF
#undef STAGE
#undef LDV
#undef QKM
#undef SPV

  // per-output-row final running max; full row denom (sum over 4 lg-lanes)
  float m_or[4];
#pragma unroll
  for (int i = 0; i < 4; ++i) m_or[i] = __shfl(m_s, lg * 4 + i, 64);
  float su_row = su_s;
  su_row += __shfl_xor(su_row, 16, 64);
  su_row += __shfl_xor(su_row, 32, 64);

  // ------- LSE merge of the 4 per-wave partials (OB aliases BUF) -------
  float (*OB)[16][68] = (float (*)[16][68])BUF;  // 4*16*68*4 = 17408 B
  if (l < 16) {  // lg==0 lanes cover lr=0..15
    Sm[w][l] = m_s;
    Sl[w][l] = su_row;
  }
  __syncthreads();  // also fences last K reads before BUF reuse
#pragma unroll
  for (int i = 0; i < 4; ++i) {
    const int row = lg * 4 + i;
    float M = fmaxf(fmaxf(Sm[0][row], Sm[1][row]),
                    fmaxf(Sm[2][row], Sm[3][row]));
    const float sc = __expf(m_or[i] - M);  // 0 if this wave was idle
    OB[w][row][lr] = o0[i] * sc;
    OB[w][row][16 + lr] = o1[i] * sc;
    OB[w][row][32 + lr] = o2[i] * sc;
    OB[w][row][48 + lr] = o3[i] * sc;
    if (w == 0 && lr == 0) {
      float denom = 0.f;
#pragma unroll
      for (int w2 = 0; w2 < 4; ++w2)
        denom += Sl[w2][row] * __expf(Sm[w2][row] - M);
      Dinv[row] = 1.0f / denom;
    }
  }
  __syncthreads();
  const int t2 = threadIdx.x;
#pragma unroll
  for (int k2 = 0; k2 < 4; ++k2) {
    const int e2 = t2 + 256 * k2;
    const int row = e2 >> 6, col = e2 & 63;
    const float s = OB[0][row][col] + OB[1][row][col] + OB[2][row][col] +
                    OB[3][row][col];
    out[((size_t)b * TT + q0 + row) * 64 + col] = s * Dinv[row];
  }
}

// ------------------------------------------------------------------ launch ---
extern "C" void kernel_launch(void* const* d_in, const int* in_sizes, int n_in,
                              void* d_out, int out_size, void* d_ws,
                              size_t ws_size, hipStream_t stream) {
  const float* x = (const float*)d_in[0];
  const float* Wq = (const float*)d_in[1];
  const float* Wk = (const float*)d_in[2];
  const float* Wv = (const float*)d_in[3];
  float* out = (float*)d_out;
  char* ws = (char*)d_ws;

  size_t off = 0;
  __bf16* WC = (__bf16*)(ws + off); off += (size_t)64 * WSLICE_S * 2;  // 655KB
  __bf16* qh = (__bf16*)(ws + off); off += (size_t)NROW * 64 * 2;
  __bf16* ql = (__bf16*)(ws + off); off += (size_t)NROW * 64 * 2;
  __bf16* kh = (__bf16*)(ws + off); off += (size_t)NROW * 64 * 2;
  __bf16* kl = (__bf16*)(ws + off); off += (size_t)NROW * 64 * 2;
  __bf16* vt = (__bf16*)(ws + off); off += (size_t)NROW * 64 * 2;  // ~11.1 MB

  wprep_kernel<<<dim3(32), dim3(256), 0, stream>>>(Wq, Wk, Wv, WC);
  proj_kernel<<<dim3(512), dim3(512), 0, stream>>>(
      x, WC, qh, ql, kh, kl, vt);
  attn_kernel<<<dim3(1024), dim3(256), 0, stream>>>(
      qh, ql, kh, kl, vt, out);
}

// Round 20
// 78.820 us; speedup vs baseline: 1.0601x; 1.0601x over previous
//
#include <hip/hip_runtime.h>
#include <hip/hip_bf16.h>

// MaskedAttention: out = softmax(tril(q k^T)) v, q/k/v = x @ W{q,k,v}
// B=8 T=2048 D=1024 H=64, fp32 in/out, no 1/sqrt(H) scaling.
//
// Precision plan: q,k projections and QK^T use hi/lo bf16 splitting
// (3-MFMA "bf16x3") so logits are ~fp32-accurate; V/P plain bf16.

typedef __bf16 bf16x8 __attribute__((ext_vector_type(8)));
typedef float f32x4 __attribute__((ext_vector_type(4)));

#define MFMA16(a, b, c) __builtin_amdgcn_mfma_f32_16x16x32_bf16((a), (b), (c), 0, 0, 0)
#define SB0() __builtin_amdgcn_sched_barrier(0)

static constexpr int BB = 8;
static constexpr int TT = 2048;
static constexpr int DD = 1024;
static constexpr int HH = 64;
static constexpr int NROW = BB * TT;       // 16384
// WC slab: [4 colgroups][8 K-eighths][80 rows = k8l*5+frag][16 cols][8 bf16]
// frag: 0=q_hi 1=q_lo 2=k_hi 3=k_lo 4=v_hi. 20KB per (cg,eighth) slice.
static constexpr int WSLICE_E = 80 * 128;  // bf16 elems per (cg,eighth)

// pack two floats to one u32 of 2 bf16 (lo, hi)
__device__ __forceinline__ unsigned pk2(float a, float b) {
  union { __bf16 h[2]; unsigned u; } r;
  r.h[0] = (__bf16)a;
  r.h[1] = (__bf16)b;
  return r.u;
}

// ---------------------------------------------------------------- W prep ---
// W [1024][64] fp32 -> WC slab (see above). Linear in (row,col) so proj can
// stage it to LDS with pure linear global_load_lds DMA.
__global__ __launch_bounds__(256) void wprep_kernel(
    const float* __restrict__ Wq, const float* __restrict__ Wk,
    const float* __restrict__ Wv, __bf16* __restrict__ WC) {
  int tid = blockIdx.x * 256 + threadIdx.x;
  if (tid >= 64 * 128) return;
  int col = tid >> 7;
  int k8 = tid & 127;
  const int g = col >> 4, c = col & 15;
  const int e8 = k8 >> 4, k8l = k8 & 15;  // eighth, local k8
  bf16x8 q_h, q_l, k_h, k_l, v_h;
#pragma unroll
  for (int j = 0; j < 8; ++j) {
    const int k = k8 * 8 + j;
    float qv = Wq[k * 64 + col];
    float kv = Wk[k * 64 + col];
    float vv = Wv[k * 64 + col];
    __bf16 qhi = (__bf16)qv;
    __bf16 khi = (__bf16)kv;
    q_h[j] = qhi;
    q_l[j] = (__bf16)(qv - (float)qhi);
    k_h[j] = khi;
    k_l[j] = (__bf16)(kv - (float)khi);
    v_h[j] = (__bf16)vv;
  }
  __bf16* base = WC + (size_t)(g * 8 + e8) * WSLICE_E +
                 (size_t)(k8l * 5) * 128 + c * 8;
  *(bf16x8*)(base) = q_h;            // row k8l*5+0
  *(bf16x8*)(base + 128) = q_l;      // row k8l*5+1
  *(bf16x8*)(base + 256) = k_h;      // row k8l*5+2
  *(bf16x8*)(base + 384) = k_l;      // row k8l*5+3
  *(bf16x8*)(base + 512) = v_h;      // row k8l*5+4
}

// ------------------------------------------------------------ projection ---
// Block = 256 threads (4 waves): 64 rows x ONE 16-col group, K in 8
// eighths. This is the R16 structure (proj best: 46.7us) geometrically
// rescaled so the GRID supplies the barrier-overlap blocks R16's LDS cut
// enabled: 1024 blocks (256 rg x 4 cg), LDS 36.8KB -> 4 blocks/CU
// resident (R16: grid 512 = only 2/CU -> capacity unused). 16 waves/CU
// (the structural max) with 4 barrier-partner blocks: when one block
// waits at its per-step barrier, three others issue. All mechanisms
// (W-eighth staging, X XOR swizzle rule #21, barrier schedule) identical
// to the passing R16 kernel, geometry rescaled. W-staging L2 traffic
// doubles (+2.4us) -- accepted for the overlap gain.
__global__ __launch_bounds__(256, 4) void proj_kernel(
    const float* __restrict__ x, const __bf16* __restrict__ WC,
    __bf16* __restrict__ qh, __bf16* __restrict__ ql,
    __bf16* __restrict__ kh, __bf16* __restrict__ kl,
    __bf16* __restrict__ vt) {
  __shared__ __bf16 Wlds[WSLICE_E];   // 20 KB
  __shared__ float Xlds[2][2048];     // 2 x 8 KB (64 rows x 32 floats)
  const int tid = threadIdx.x;
  const int w = tid >> 6, l = tid & 63;
  const int lr = l & 15, lg = l >> 4;
  const int rg = blockIdx.x & 255, cg = blockIdx.x >> 8;
  const int r0 = rg * 64 + w * 16;
  const int R_ = w * 16 + lr;  // this lane's x row within the block (0..63)
  // per-frag W LDS base (bf16 elems): row (5*lg+m), chunk lr
  const int wb0 = (5 * lg) * 128 + lr * 8;

  f32x4 aq = {0.f, 0.f, 0.f, 0.f};
  f32x4 ak = {0.f, 0.f, 0.f, 0.f};
  f32x4 av = {0.f, 0.f, 0.f, 0.f};

  // x chunk layout in LDS: float (R,kk) at byte R*128 + ((kk>>2)^(R&7))*16
  // + (kk&3)*4.  DMA dest linear (base + i_*4096 + w*1024; lane x16
  // implicit -> byte i_*4096 + tid*16 = row (i_*32 + tid>>3), slot tid&7);
  // source group pre-swizzled g = (tid&7)^((tid>>3)&7)  (rule #21).
#define STAGEX(B, KGLOB)                                                \
  do {                                                                  \
    _Pragma("unroll") for (int i_ = 0; i_ < 2; ++i_) {                  \
      const float* xs_ = x +                                            \
          (size_t)(rg * 64 + i_ * 32 + (tid >> 3)) * 1024 +             \
          (KGLOB) + (((tid & 7) ^ ((tid >> 3) & 7)) << 2);              \
      __builtin_amdgcn_global_load_lds(                                 \
          (const __attribute__((address_space(1))) unsigned int*)xs_,   \
          (__attribute__((address_space(3))) unsigned int*)             \
              ((char*)Xlds + (B) * 8192 + i_ * 4096 + w * 1024),        \
          16, 0, 0);                                                    \
    }                                                                   \
  } while (0)

#define CMPSTEP(S, B)                                                   \
  do {                                                                  \
    const __bf16* fp = &Wlds[(S) * 2560 + wb0];                         \
    bf16x8 f0 = *(const bf16x8*)(fp);                                   \
    bf16x8 f1 = *(const bf16x8*)(fp + 128);                             \
    bf16x8 f2 = *(const bf16x8*)(fp + 256);                             \
    bf16x8 f3 = *(const bf16x8*)(fp + 384);                             \
    bf16x8 f4 = *(const bf16x8*)(fp + 512);                             \
    const char* xb_ = (const char*)Xlds + (B) * 8192 + R_ * 128;        \
    const float4 xA = *(const float4*)(xb_ + (((lg * 2) ^ (R_ & 7)) << 4)); \
    const float4 xB = *(const float4*)(xb_ + (((lg * 2 + 1) ^ (R_ & 7)) << 4)); \
    float xs[8] = {xA.x, xA.y, xA.z, xA.w, xB.x, xB.y, xB.z, xB.w};     \
    bf16x8 ah, al;                                                      \
    _Pragma("unroll") for (int j = 0; j < 8; ++j) {                     \
      __bf16 hv = (__bf16)xs[j];                                        \
      ah[j] = hv;                                                       \
      al[j] = (__bf16)(xs[j] - (float)hv);                              \
    }                                                                   \
    aq = MFMA16(ah, f0, aq);                                            \
    aq = MFMA16(ah, f1, aq);                                            \
    aq = MFMA16(al, f0, aq);                                            \
    ak = MFMA16(ah, f2, ak);                                            \
    ak = MFMA16(ah, f3, ak);                                            \
    ak = MFMA16(al, f2, ak);                                            \
    av = MFMA16(ah, f4, av);                                            \
  } while (0)

  STAGEX(0, 0);  // chunk 0 in flight alongside the first W stage
#pragma unroll 1
  for (int e = 0; e < 8; ++e) {
    if (e) __syncthreads();  // all waves done with W[e-1] + old X bufs
    {
      // stage the 20KB W eighth: 256 threads x 5 x 16B loads (linear)
      const __bf16* wsrc = WC + (size_t)(cg * 8 + e) * WSLICE_E;
      const __bf16* gp = wsrc + (size_t)tid * 8;  // per-lane 16B cell
#pragma unroll
      for (int i2 = 0; i2 < 5; ++i2) {
        __builtin_amdgcn_global_load_lds(
            (const __attribute__((address_space(1))) unsigned int*)(gp + i2 * 2048),
            (__attribute__((address_space(3))) unsigned int*)
                ((char*)Wlds + w * 1024 + i2 * 4096),
            16, 0, 0);
      }
    }
#pragma unroll
    for (int s = 0; s < 4; ++s) {
      __syncthreads();  // drains W (s==0) + x chunk e*4+s (issued 1 step ago)
      if (!(e == 7 && s == 3))
        STAGEX((s + 1) & 1, e * 128 + (s + 1) * 32);  // crosses boundaries
      CMPSTEP(s, s & 1);
    }
  }
#undef STAGEX
#undef CMPSTEP

#pragma unroll
  for (int i = 0; i < 4; ++i) {
    const int row = r0 + lg * 4 + i;  // C-layout: row=(lane>>4)*4+reg
    const int col = cg * 16 + lr;     //           col=lane&15
    const size_t oq = (size_t)row * 64 + col;
    float qv = aq[i];
    __bf16 qhi = (__bf16)qv;
    qh[oq] = qhi;
    ql[oq] = (__bf16)(qv - (float)qhi);
    float kv = ak[i];
    __bf16 khi = (__bf16)kv;
    kh[oq] = khi;
    kl[oq] = (__bf16)(kv - (float)khi);
    const int bb = row >> 11, tt = row & 2047;
    vt[((size_t)bb * 64 + col) * 2048 + tt] = (__bf16)av[i];
  }
}

// -------------------------------------------------------------- attention ---
// Split-K flash, 4-wave blocks, K STAGED THROUGH LDS (R12: 63 -> ~32us).
// 128-key supersteps; all 256 threads DMA kh+kl (32KB) to LDS with XOR-
// pre-swizzled source (rule #21); ONE vmcnt drain per superstep; V (4
// loads, 16 reg) issued before the drain so its latency hides under it.
// K-LDS buffer aliased with the post-loop merge buffer: LDS 33.5KB ->
// 4 blocks/CU, all 1024 blocks resident, b=bid&7 XCD affinity preserved.
__global__ __launch_bounds__(256, 4) void attn_kernel(
    const __bf16* __restrict__ qh, const __bf16* __restrict__ ql,
    const __bf16* __restrict__ kh, const __bf16* __restrict__ kl,
    const __bf16* __restrict__ vt, float* __restrict__ out) {
  __shared__ char BUF[32768] __attribute__((aligned(16)));  // K stage / merge
  __shared__ float Sm[4][16];       // per-wave row maxes
  __shared__ float Sl[4][16];       // per-wave row sums
  __shared__ float Dinv[16];        // 1/denom per row
  const int w = threadIdx.x >> 6, l = threadIdx.x & 63;
  const int lr = l & 15, lg = l >> 4;
  const int b = blockIdx.x & 7;            // XCD affinity: batch -> XCD
  const int qt = 127 - (blockIdx.x >> 3);  // heavy tiles first
  const int q0 = qt * 16;
  const float NEG = -__builtin_inff();

  // Q fragments (B-operand of the swapped QK^T)
  const size_t qb = ((size_t)b * TT + q0 + lr) * 64 + lg * 8;
  const bf16x8 fqh0 = *(const bf16x8*)(qh + qb);
  const bf16x8 fqh1 = *(const bf16x8*)(qh + qb + 32);
  const bf16x8 fql0 = *(const bf16x8*)(ql + qb);
  const bf16x8 fql1 = *(const bf16x8*)(ql + qb + 32);

  f32x4 o0 = {0.f, 0.f, 0.f, 0.f}, o1 = o0, o2 = o0, o3 = o0;
  float m_s = NEG;   // running max for q-row (q0+lr), shared by 4 lg-lanes
  float su_s = 0.f;  // partial denom for q-row (this lane's keys only)
  const int nkt = (q0 + 47) >> 5;    // ceil((q0+16)/32)
  const int nsup = (nkt + 3) >> 2;   // 128-key supersteps

  bf16x8 v0, v1, v2, v3;
  f32x4 sa, sb;

  // LDS element offset for logical (row r, colgroup c) with XOR swizzle.
  // kh rows at bf16 index 0.., kl at +8192 (byte 16384).
#define KOFF(R, C) ((R) * 64 + ((((C) ^ ((R)&7))) * 8))

  // Stage kh+kl for keys [sup*128, +128) into BUF. Dest is linear
  // (slot = w*1024 + i*4096 + lane*16 -> row w*8+i*32+(l>>3), cg l&7);
  // source colgroup pre-swizzled: (l&7)^(l>>3) since row&7 == l>>3.
#define STAGE(SUP)                                                         \
  do {                                                                     \
    const size_t kbase_ = ((size_t)b * TT + (size_t)(SUP) * 128) * 64;     \
    const size_t rowco_ = (size_t)(w * 8 + (l >> 3)) * 64 +                \
                          (size_t)(((l & 7) ^ (l >> 3)) * 8);              \
    const __bf16* srck_ = kh + kbase_ + rowco_;                            \
    const __bf16* srcl_ = kl + kbase_ + rowco_;                            \
    _Pragma("unroll") for (int i_ = 0; i_ < 4; ++i_) {                     \
      __builtin_amdgcn_global_load_lds(                                    \
          (const __attribute__((address_space(1))) unsigned int*)(srck_ + i_ * 2048), \
          (__attribute__((address_space(3))) unsigned int*)(BUF + w * 1024 + i_ * 4096), \
          16, 0, 0);                                                       \
    }                                                                      \
    _Pragma("unroll") for (int i_ = 0; i_ < 4; ++i_) {                     \
      __builtin_amdgcn_global_load_lds(                                    \
          (const __attribute__((address_space(1))) unsigned int*)(srcl_ + i_ * 2048), \
          (__attribute__((address_space(3))) unsigned int*)(BUF + 16384 + w * 1024 + i_ * 4096), \
          16, 0, 0);                                                       \
    }                                                                      \
  } while (0)

#define LDV(KT)                                                        \
  do {                                                                 \
    const size_t vb_ =                                                 \
        ((size_t)b * 64 + lr) * 2048 + (KT) * 32 + lg * 8;             \
    v0 = *(const bf16x8*)(vt + vb_);                                   \
    v1 = *(const bf16x8*)(vt + vb_ + (size_t)16 * 2048);               \
    v2 = *(const bf16x8*)(vt + vb_ + (size_t)32 * 2048);               \
    v3 = *(const bf16x8*)(vt + vb_ + (size_t)48 * 2048);               \
  } while (0)

  // QK^T from LDS K (wave w's 32-key tile = buffer rows w*32..w*32+31).
#define QKM(KT)                                                        \
  do {                                                                 \
    const int j0_ = (KT) * 32;                                         \
    const int rA_ = w * 32 + lr, rB_ = rA_ + 16;                       \
    const __bf16* Kb_ = (const __bf16*)BUF;                            \
    const bf16x8 fk0 = *(const bf16x8*)(Kb_ + KOFF(rA_, lg));          \
    const bf16x8 fk1 = *(const bf16x8*)(Kb_ + KOFF(rA_, 4 + lg));      \
    const bf16x8 fl0 = *(const bf16x8*)(Kb_ + 8192 + KOFF(rA_, lg));   \
    const bf16x8 fl1 = *(const bf16x8*)(Kb_ + 8192 + KOFF(rA_, 4 + lg)); \
    const bf16x8 gk0 = *(const bf16x8*)(Kb_ + KOFF(rB_, lg));          \
    const bf16x8 gk1 = *(const bf16x8*)(Kb_ + KOFF(rB_, 4 + lg));      \
    const bf16x8 gl0 = *(const bf16x8*)(Kb_ + 8192 + KOFF(rB_, lg));   \
    const bf16x8 gl1 = *(const bf16x8*)(Kb_ + 8192 + KOFF(rB_, 4 + lg)); \
    const f32x4 z_ = {0.f, 0.f, 0.f, 0.f};                             \
    {                                                                  \
      f32x4 c0_ = MFMA16(fk1, fqh1, MFMA16(fk0, fqh0, z_));            \
      f32x4 c1_ = MFMA16(fk1, fql1, MFMA16(fk0, fql0, z_));            \
      f32x4 c2_ = MFMA16(fl1, fqh1, MFMA16(fl0, fqh0, z_));            \
      sa = c0_ + c1_ + c2_;                                            \
    }                                                                  \
    sb = (f32x4){NEG, NEG, NEG, NEG};                                  \
    if ((j0_ + 16) <= (q0 + 15)) {                                     \
      f32x4 c0_ = MFMA16(gk1, fqh1, MFMA16(gk0, fqh0, z_));            \
      f32x4 c1_ = MFMA16(gk1, fql1, MFMA16(gk0, fql0, z_));            \
      f32x4 c2_ = MFMA16(gl1, fqh1, MFMA16(gl0, fqh0, z_));            \
      sb = c0_ + c1_ + c2_;                                            \
    }                                                                  \
    _Pragma("unroll") for (int i = 0; i < 4; ++i) {                    \
      if (j0_ + lg * 4 + i > q0 + lr) sa[i] = NEG;                     \
      if (j0_ + 16 + lg * 4 + i > q0 + lr) sb[i] = NEG;                \
    }                                                                  \
  } while (0)

#define SPV()                                                          \
  do {                                                                 \
    float t_ = fmaxf(fmaxf(fmaxf(sa[0], sa[1]), fmaxf(sa[2], sa[3])),  \
                     fmaxf(fmaxf(sb[0], sb[1]), fmaxf(sb[2], sb[3]))); \
    t_ = fmaxf(t_, __shfl_xor(t_, 16, 64));                            \
    t_ = fmaxf(t_, __shfl_xor(t_, 32, 64));                            \
    const float mn_ = fmaxf(m_s, t_);                                  \
    const float sc_ = __expf(m_s - mn_);                               \
    m_s = mn_;                                                         \
    const float pa0_ = __expf(sa[0] - mn_), pa1_ = __expf(sa[1] - mn_);\
    const float pa2_ = __expf(sa[2] - mn_), pa3_ = __expf(sa[3] - mn_);\
    const float pb0_ = __expf(sb[0] - mn_), pb1_ = __expf(sb[1] - mn_);\
    const float pb2_ = __expf(sb[2] - mn_), pb3_ = __expf(sb[3] - mn_);\
    su_s = su_s * sc_ + ((pa0_ + pa1_) + (pa2_ + pa3_)) +              \
           ((pb0_ + pb1_) + (pb2_ + pb3_));                            \
    _Pragma("unroll") for (int i = 0; i < 4; ++i) {                    \
      const float scr_ = __shfl(sc_, lg * 4 + i, 64);                  \
      o0[i] *= scr_; o1[i] *= scr_; o2[i] *= scr_; o3[i] *= scr_;      \
    }                                                                  \
    const unsigned x0_ = pk2(pa0_, pa1_), x1_ = pk2(pa2_, pa3_);       \
    const unsigned y0_ = pk2(pb0_, pb1_), y1_ = pk2(pb2_, pb3_);       \
    const bool e_ = (lg & 1) != 0;                                     \
    const unsigned s0_ = e_ ? x0_ : y0_, s1_ = e_ ? x1_ : y1_;         \
    const unsigned r0_ = __shfl_xor(s0_, 16, 64);                      \
    const unsigned r1_ = __shfl_xor(s1_, 16, 64);                      \
    unsigned z0_ = e_ ? r0_ : x0_;                                     \
    unsigned z1_ = e_ ? r1_ : x1_;                                     \
    unsigned z2_ = e_ ? y0_ : r0_;                                     \
    unsigned z3_ = e_ ? y1_ : r1_;                                     \
    const unsigned u0_ = __shfl_xor(z0_, 48, 64);                      \
    const unsigned u1_ = __shfl_xor(z1_, 48, 64);                      \
    const unsigned u2_ = __shfl_xor(z2_, 48, 64);                      \
    const unsigned u3_ = __shfl_xor(z3_, 48, 64);                      \
    const bool sw_ = (lg == 1) || (lg == 2);                           \
    z0_ = sw_ ? u0_ : z0_; z1_ = sw_ ? u1_ : z1_;                      \
    z2_ = sw_ ? u2_ : z2_; z3_ = sw_ ? u3_ : z3_;                      \
    union { unsigned u[4]; bf16x8 v; } pfu_;                           \
    pfu_.u[0] = z0_; pfu_.u[1] = z1_;                                  \
    pfu_.u[2] = z2_; pfu_.u[3] = z3_;                                  \
    const bf16x8 pf_ = pfu_.v;                                         \
    o0 = MFMA16(pf_, v0, o0);                                          \
    o1 = MFMA16(pf_, v1, o1);                                          \
    o2 = MFMA16(pf_, v2, o2);                                          \
    o3 = MFMA16(pf_, v3, o3);                                          \
  } while (0)

#pragma unroll 1
  for (int sup = 0; sup < nsup; ++sup) {
    if (sup) __syncthreads();        // waves done reading previous K tiles
    STAGE(sup);                      // DMA kh+kl (32KB) -> BUF
    const int kt = sup * 4 + w;      // this wave's tile in the superstep
    const bool act = kt < nkt;       // wave-uniform
    if (act) LDV(kt);                // V in regs; hidden under the drain
    __syncthreads();                 // vmcnt(0) drain: DMA + V complete
    if (act) {
      QKM(kt);                       // K frags from LDS (swizzled ds_read)
      SPV();
    }
  }
#undef KOFF
#undef STAGE
#undef LDV
#undef QKM
#undef SPV

  // per-output-row final running max; full row denom (sum over 4 lg-lanes)
  float m_or[4];
#pragma unroll
  for (int i = 0; i < 4; ++i) m_or[i] = __shfl(m_s, lg * 4 + i, 64);
  float su_row = su_s;
  su_row += __shfl_xor(su_row, 16, 64);
  su_row += __shfl_xor(su_row, 32, 64);

  // ------- LSE merge of the 4 per-wave partials (OB aliases BUF) -------
  float (*OB)[16][68] = (float (*)[16][68])BUF;  // 4*16*68*4 = 17408 B
  if (l < 16) {  // lg==0 lanes cover lr=0..15
    Sm[w][l] = m_s;
    Sl[w][l] = su_row;
  }
  __syncthreads();  // also fences last K reads before BUF reuse
#pragma unroll
  for (int i = 0; i < 4; ++i) {
    const int row = lg * 4 + i;
    float M = fmaxf(fmaxf(Sm[0][row], Sm[1][row]),
                    fmaxf(Sm[2][row], Sm[3][row]));
    const float sc = __expf(m_or[i] - M);  // 0 if this wave was idle
    OB[w][row][lr] = o0[i] * sc;
    OB[w][row][16 + lr] = o1[i] * sc;
    OB[w][row][32 + lr] = o2[i] * sc;
    OB[w][row][48 + lr] = o3[i] * sc;
    if (w == 0 && lr == 0) {
      float denom = 0.f;
#pragma unroll
      for (int w2 = 0; w2 < 4; ++w2)
        denom += Sl[w2][row] * __expf(Sm[w2][row] - M);
      Dinv[row] = 1.0f / denom;
    }
  }
  __syncthreads();
  const int t2 = threadIdx.x;
#pragma unroll
  for (int k2 = 0; k2 < 4; ++k2) {
    const int e2 = t2 + 256 * k2;
    const int row = e2 >> 6, col = e2 & 63;
    const float s = OB[0][row][col] + OB[1][row][col] + OB[2][row][col] +
                    OB[3][row][col];
    out[((size_t)b * TT + q0 + row) * 64 + col] = s * Dinv[row];
  }
}

// ------------------------------------------------------------------ launch ---
extern "C" void kernel_launch(void* const* d_in, const int* in_sizes, int n_in,
                              void* d_out, int out_size, void* d_ws,
                              size_t ws_size, hipStream_t stream) {
  const float* x = (const float*)d_in[0];
  const float* Wq = (const float*)d_in[1];
  const float* Wk = (const float*)d_in[2];
  const float* Wv = (const float*)d_in[3];
  float* out = (float*)d_out;
  char* ws = (char*)d_ws;

  size_t off = 0;
  __bf16* WC = (__bf16*)(ws + off); off += (size_t)32 * WSLICE_E * 2;  // 655KB
  __bf16* qh = (__bf16*)(ws + off); off += (size_t)NROW * 64 * 2;
  __bf16* ql = (__bf16*)(ws + off); off += (size_t)NROW * 64 * 2;
  __bf16* kh = (__bf16*)(ws + off); off += (size_t)NROW * 64 * 2;
  __bf16* kl = (__bf16*)(ws + off); off += (size_t)NROW * 64 * 2;
  __bf16* vt = (__bf16*)(ws + off); off += (size_t)NROW * 64 * 2;  // ~11.1 MB

  wprep_kernel<<<dim3(32), dim3(256), 0, stream>>>(Wq, Wk, Wv, WC);
  proj_kernel<<<dim3(1024), dim3(256), 0, stream>>>(
      x, WC, qh, ql, kh, kl, vt);
  attn_kernel<<<dim3(1024), dim3(256), 0, stream>>>(
      qh, ql, kh, kl, vt, out);
}

// Round 21
// 73.078 us; speedup vs baseline: 1.1434x; 1.0786x over previous
//
#include <hip/hip_runtime.h>
#include <hip/hip_bf16.h>

// MaskedAttention: out = softmax(tril(q k^T)) v, q/k/v = x @ W{q,k,v}
// B=8 T=2048 D=1024 H=64, fp32 in/out, no 1/sqrt(H) scaling.
//
// Precision plan: q,k projections and QK^T use hi/lo bf16 splitting
// (3-MFMA "bf16x3") so logits are ~fp32-accurate; V/P plain bf16.
//
// FINAL (R21): reverted to the session-best R17 configuration (73.1us).
// Session ledger: 236.5 -> 73.1us. proj is at a structural plateau
// (46-52us across 7 schedule variants, no pipe >40% busy); attn at its
// analogous floor (~32us). Remaining gap is per-step latency/coordination
// the compiler does not compress at HIP source level.

typedef __bf16 bf16x8 __attribute__((ext_vector_type(8)));
typedef float f32x4 __attribute__((ext_vector_type(4)));

#define MFMA16(a, b, c) __builtin_amdgcn_mfma_f32_16x16x32_bf16((a), (b), (c), 0, 0, 0)
#define SB0() __builtin_amdgcn_sched_barrier(0)
#define WAITV_(N) asm volatile("s_waitcnt vmcnt(" #N ")" ::: "memory")
#define WAITV(N) WAITV_(N)

static constexpr int BB = 8;
static constexpr int TT = 2048;
static constexpr int DD = 1024;
static constexpr int HH = 64;
static constexpr int NROW = BB * TT;       // 16384
// WC slab: [4 colgroups][16 K-16ths][40 rows = k8l*5+frag][16 cols][8 bf16]
// frag: 0=q_hi 1=q_lo 2=k_hi 3=k_lo 4=v_hi. 10KB per (cg,16th) slice.
static constexpr int WSLICE_S = 40 * 128;  // 5120 bf16 per (cg,16th)

// pack two floats to one u32 of 2 bf16 (lo, hi)
__device__ __forceinline__ unsigned pk2(float a, float b) {
  union { __bf16 h[2]; unsigned u; } r;
  r.h[0] = (__bf16)a;
  r.h[1] = (__bf16)b;
  return r.u;
}

// ---------------------------------------------------------------- W prep ---
// W [1024][64] fp32 -> WC slab (see above). Linear in (row,col) so proj can
// stage it to LDS with pure linear global_load_lds DMA.
__global__ __launch_bounds__(256) void wprep_kernel(
    const float* __restrict__ Wq, const float* __restrict__ Wk,
    const float* __restrict__ Wv, __bf16* __restrict__ WC) {
  int tid = blockIdx.x * 256 + threadIdx.x;
  if (tid >= 64 * 128) return;
  int col = tid >> 7;
  int k8 = tid & 127;
  const int g = col >> 4, c = col & 15;
  const int f = k8 >> 3, k8l = k8 & 7;  // sixteenth, local k8
  bf16x8 q_h, q_l, k_h, k_l, v_h;
#pragma unroll
  for (int j = 0; j < 8; ++j) {
    const int k = k8 * 8 + j;
    float qv = Wq[k * 64 + col];
    float kv = Wk[k * 64 + col];
    float vv = Wv[k * 64 + col];
    __bf16 qhi = (__bf16)qv;
    __bf16 khi = (__bf16)kv;
    q_h[j] = qhi;
    q_l[j] = (__bf16)(qv - (float)qhi);
    k_h[j] = khi;
    k_l[j] = (__bf16)(kv - (float)khi);
    v_h[j] = (__bf16)vv;
  }
  __bf16* base = WC + (size_t)(g * 16 + f) * WSLICE_S +
                 (size_t)(k8l * 5) * 128 + c * 8;
  *(bf16x8*)(base) = q_h;            // row k8l*5+0
  *(bf16x8*)(base + 128) = q_l;      // row k8l*5+1
  *(bf16x8*)(base + 256) = k_h;      // row k8l*5+2
  *(bf16x8*)(base + 384) = k_l;      // row k8l*5+3
  *(bf16x8*)(base + 512) = v_h;      // row k8l*5+4
}

// ------------------------------------------------------------ projection ---
// Block = 512 threads (8 waves): 128 rows x ONE 16-col group. RAW s_barrier
// + counted s_waitcnt schedule (T3/T4): X triple-buffered (chunk s+2 issued
// at step s = ~800cy cover, steady-state vmcnt(2)); W sliced in sixteenths,
// DOUBLE-buffered (W_{f+1} prefetched 2 steps early by waves 0-1, 5 loads
// each). FIFO-derived waits: waves 0-1 vmcnt(2) even steps / vmcnt(7) odd
// (C(s+1)+W in flight), waves 2-7 vmcnt(2), last step vmcnt(0).
// Wait BEFORE barrier (publish own DMA), issue AFTER barrier (WAR safety),
// SB0 after barrier (rule #18). LDS 68KB -> 2 blocks/CU (= grid supply).
// Grid 512: rg=bid&127, cg=bid>>7 -> same-x blocks share an XCD L2.
__global__ __launch_bounds__(512, 4) void proj_kernel(
    const float* __restrict__ x, const __bf16* __restrict__ WC,
    __bf16* __restrict__ qh, __bf16* __restrict__ ql,
    __bf16* __restrict__ kh, __bf16* __restrict__ kl,
    __bf16* __restrict__ vt) {
  __shared__ __bf16 Wlds[2][WSLICE_S];  // 2 x 10 KB
  __shared__ float Xlds[3][4096];       // 3 x 16 KB (128 rows x 32 floats)
  const int tid = threadIdx.x;
  const int w = tid >> 6, l = tid & 63;
  const int lr = l & 15, lg = l >> 4;
  const int rg = blockIdx.x & 127, cg = blockIdx.x >> 7;
  const int r0 = rg * 128 + w * 16;
  const int R_ = w * 16 + lr;  // this lane's x row within the block
  // per-frag W LDS base (bf16 elems): row (5*lg+m), chunk lr
  const int wb0 = (5 * lg) * 128 + lr * 8;

  f32x4 aq = {0.f, 0.f, 0.f, 0.f};
  f32x4 ak = {0.f, 0.f, 0.f, 0.f};
  f32x4 av = {0.f, 0.f, 0.f, 0.f};

  // x chunk layout in LDS: float (R,kk) at byte R*128 + ((kk>>2)^(R&7))*16
  // + (kk&3)*4.  DMA dest linear (wave-uniform base; lane x16 implicit);
  // source group pre-swizzled g = (tid&7)^((tid>>3)&7)  (rule #21).
#define STAGEX(B, KGLOB)                                                \
  do {                                                                  \
    const float* xs0_ = x + (size_t)(rg * 128 + (tid >> 3)) * 1024 +    \
                        (KGLOB) + (((tid & 7) ^ ((tid >> 3) & 7)) << 2);\
    __builtin_amdgcn_global_load_lds(                                   \
        (const __attribute__((address_space(1))) unsigned int*)xs0_,    \
        (__attribute__((address_space(3))) unsigned int*)               \
            ((char*)Xlds + (B) * 16384 + w * 1024),                     \
        16, 0, 0);                                                      \
    __builtin_amdgcn_global_load_lds(                                   \
        (const __attribute__((address_space(1))) unsigned int*)(xs0_ + 65536), \
        (__attribute__((address_space(3))) unsigned int*)               \
            ((char*)Xlds + (B) * 16384 + w * 1024 + 8192),              \
        16, 0, 0);                                                      \
  } while (0)

  // stage one 10KB W sixteenth: waves 0-1 only, 5 x 16B per thread, linear
#define STAGEW(WB, F)                                                   \
  do {                                                                  \
    const __bf16* wsrc_ = WC + (size_t)(cg * 16 + (F)) * WSLICE_S +     \
                          (size_t)tid * 8;                              \
    _Pragma("unroll") for (int i_ = 0; i_ < 5; ++i_) {                  \
      __builtin_amdgcn_global_load_lds(                                 \
          (const __attribute__((address_space(1))) unsigned int*)(wsrc_ + i_ * 1024), \
          (__attribute__((address_space(3))) unsigned int*)             \
              ((char*)Wlds + (WB) * 10240 + w * 1024 + i_ * 2048),      \
          16, 0, 0);                                                    \
    }                                                                   \
  } while (0)

#define CMPSTEP(SS)                                                     \
  do {                                                                  \
    const __bf16* fp = &Wlds[((SS) >> 1) & 1][((SS)&1) * 2560 + wb0];   \
    bf16x8 f0 = *(const bf16x8*)(fp);                                   \
    bf16x8 f1 = *(const bf16x8*)(fp + 128);                             \
    bf16x8 f2 = *(const bf16x8*)(fp + 256);                             \
    bf16x8 f3 = *(const bf16x8*)(fp + 384);                             \
    bf16x8 f4 = *(const bf16x8*)(fp + 512);                             \
    const char* xb_ = (const char*)Xlds + ((SS) % 3) * 16384 + R_ * 128;\
    const float4 xA = *(const float4*)(xb_ + (((lg * 2) ^ (R_ & 7)) << 4)); \
    const float4 xB = *(const float4*)(xb_ + (((lg * 2 + 1) ^ (R_ & 7)) << 4)); \
    float xs[8] = {xA.x, xA.y, xA.z, xA.w, xB.x, xB.y, xB.z, xB.w};     \
    bf16x8 ah, al;                                                      \
    _Pragma("unroll") for (int j = 0; j < 8; ++j) {                     \
      __bf16 hv = (__bf16)xs[j];                                        \
      ah[j] = hv;                                                       \
      al[j] = (__bf16)(xs[j] - (float)hv);                              \
    }                                                                   \
    aq = MFMA16(ah, f0, aq);                                            \
    aq = MFMA16(ah, f1, aq);                                            \
    aq = MFMA16(al, f0, aq);                                            \
    ak = MFMA16(ah, f2, ak);                                            \
    ak = MFMA16(ah, f3, ak);                                            \
    ak = MFMA16(al, f2, ak);                                            \
    av = MFMA16(ah, f4, av);                                            \
  } while (0)

  // One step: counted wait (own DMA published) -> raw barrier -> issue
  // next-next chunk (+W prefetch on even steps) -> compute from LDS.
#define STEP(SS, VA, VB)                                                \
  do {                                                                  \
    if ((VA) == (VB)) { WAITV(VB); }                                    \
    else if (w < 2) { WAITV(VA); }                                      \
    else { WAITV(VB); }                                                 \
    __builtin_amdgcn_s_barrier();                                       \
    SB0();                                                              \
    if ((SS) + 2 < 32) STAGEX(((SS) + 2) % 3, ((SS) + 2) * 32);         \
    if ((((SS)&1) == 0) && (((SS) >> 1) + 1) < 16 && w < 2)             \
      STAGEW(((((SS) >> 1) + 1) & 1), (((SS) >> 1) + 1));               \
    CMPSTEP(SS);                                                        \
  } while (0)

  // prologue: C(0); W_0 (waves 0-1); C(1)  [FIFO matches wait ledger]
  STAGEX(0, 0);
  if (w < 2) STAGEW(0, 0);
  STAGEX(1, 32);

  STEP(0, 2, 2);  STEP(1, 7, 2);  STEP(2, 2, 2);  STEP(3, 7, 2);
  STEP(4, 2, 2);  STEP(5, 7, 2);  STEP(6, 2, 2);  STEP(7, 7, 2);
  STEP(8, 2, 2);  STEP(9, 7, 2);  STEP(10, 2, 2); STEP(11, 7, 2);
  STEP(12, 2, 2); STEP(13, 7, 2); STEP(14, 2, 2); STEP(15, 7, 2);
  STEP(16, 2, 2); STEP(17, 7, 2); STEP(18, 2, 2); STEP(19, 7, 2);
  STEP(20, 2, 2); STEP(21, 7, 2); STEP(22, 2, 2); STEP(23, 7, 2);
  STEP(24, 2, 2); STEP(25, 7, 2); STEP(26, 2, 2); STEP(27, 7, 2);
  STEP(28, 2, 2); STEP(29, 7, 2); STEP(30, 2, 2); STEP(31, 0, 0);

#undef STEP
#undef STAGEX
#undef STAGEW
#undef CMPSTEP

#pragma unroll
  for (int i = 0; i < 4; ++i) {
    const int row = r0 + lg * 4 + i;  // C-layout: row=(lane>>4)*4+reg
    const int col = cg * 16 + lr;     //           col=lane&15
    const size_t oq = (size_t)row * 64 + col;
    float qv = aq[i];
    __bf16 qhi = (__bf16)qv;
    qh[oq] = qhi;
    ql[oq] = (__bf16)(qv - (float)qhi);
    float kv = ak[i];
    __bf16 khi = (__bf16)kv;
    kh[oq] = khi;
    kl[oq] = (__bf16)(kv - (float)khi);
    const int bb = row >> 11, tt = row & 2047;
    vt[((size_t)bb * 64 + col) * 2048 + tt] = (__bf16)av[i];
  }
}

// -------------------------------------------------------------- attention ---
// Split-K flash, 4-wave blocks, K STAGED THROUGH LDS (R12: 63 -> ~32us).
// 128-key supersteps; all 256 threads DMA kh+kl (32KB) to LDS with XOR-
// pre-swizzled source (rule #21); ONE vmcnt drain per superstep; V (4
// loads, 16 reg) issued before the drain so its latency hides under it.
// K-LDS buffer aliased with the post-loop merge buffer: LDS 33.5KB ->
// 4 blocks/CU, all 1024 blocks resident, b=bid&7 XCD affinity preserved.
__global__ __launch_bounds__(256, 4) void attn_kernel(
    const __bf16* __restrict__ qh, const __bf16* __restrict__ ql,
    const __bf16* __restrict__ kh, const __bf16* __restrict__ kl,
    const __bf16* __restrict__ vt, float* __restrict__ out) {
  __shared__ char BUF[32768] __attribute__((aligned(16)));  // K stage / merge
  __shared__ float Sm[4][16];       // per-wave row maxes
  __shared__ float Sl[4][16];       // per-wave row sums
  __shared__ float Dinv[16];        // 1/denom per row
  const int w = threadIdx.x >> 6, l = threadIdx.x & 63;
  const int lr = l & 15, lg = l >> 4;
  const int b = blockIdx.x & 7;            // XCD affinity: batch -> XCD
  const int qt = 127 - (blockIdx.x >> 3);  // heavy tiles first
  const int q0 = qt * 16;
  const float NEG = -__builtin_inff();

  // Q fragments (B-operand of the swapped QK^T)
  const size_t qb = ((size_t)b * TT + q0 + lr) * 64 + lg * 8;
  const bf16x8 fqh0 = *(const bf16x8*)(qh + qb);
  const bf16x8 fqh1 = *(const bf16x8*)(qh + qb + 32);
  const bf16x8 fql0 = *(const bf16x8*)(ql + qb);
  const bf16x8 fql1 = *(const bf16x8*)(ql + qb + 32);

  f32x4 o0 = {0.f, 0.f, 0.f, 0.f}, o1 = o0, o2 = o0, o3 = o0;
  float m_s = NEG;   // running max for q-row (q0+lr), shared by 4 lg-lanes
  float su_s = 0.f;  // partial denom for q-row (this lane's keys only)
  const int nkt = (q0 + 47) >> 5;    // ceil((q0+16)/32)
  const int nsup = (nkt + 3) >> 2;   // 128-key supersteps

  bf16x8 v0, v1, v2, v3;
  f32x4 sa, sb;

  // LDS element offset for logical (row r, colgroup c) with XOR swizzle.
  // kh rows at bf16 index 0.., kl at +8192 (byte 16384).
#define KOFF(R, C) ((R) * 64 + ((((C) ^ ((R)&7))) * 8))

  // Stage kh+kl for keys [sup*128, +128) into BUF. Dest is linear
  // (slot = w*1024 + i*4096 + lane*16 -> row w*8+i*32+(l>>3), cg l&7);
  // source colgroup pre-swizzled: (l&7)^(l>>3) since row&7 == l>>3.
#define STAGE(SUP)                                                         \
  do {                                                                     \
    const size_t kbase_ = ((size_t)b * TT + (size_t)(SUP) * 128) * 64;     \
    const size_t rowco_ = (size_t)(w * 8 + (l >> 3)) * 64 +                \
                          (size_t)(((l & 7) ^ (l >> 3)) * 8);              \
    const __bf16* srck_ = kh + kbase_ + rowco_;                            \
    const __bf16* srcl_ = kl + kbase_ + rowco_;                            \
    _Pragma("unroll") for (int i_ = 0; i_ < 4; ++i_) {                     \
      __builtin_amdgcn_global_load_lds(                                    \
          (const __attribute__((address_space(1))) unsigned int*)(srck_ + i_ * 2048), \
          (__attribute__((address_space(3))) unsigned int*)(BUF + w * 1024 + i_ * 4096), \
          16, 0, 0);                                                       \
    }                                                                      \
    _Pragma("unroll") for (int i_ = 0; i_ < 4; ++i_) {                     \
      __builtin_amdgcn_global_load_lds(                                    \
          (const __attribute__((address_space(1))) unsigned int*)(srcl_ + i_ * 2048), \
          (__attribute__((address_space(3))) unsigned int*)(BUF + 16384 + w * 1024 + i_ * 4096), \
          16, 0, 0);                                                       \
    }                                                                      \
  } while (0)

#define LDV(KT)                                                        \
  do {                                                                 \
    const size_t vb_ =                                                 \
        ((size_t)b * 64 + lr) * 2048 + (KT) * 32 + lg * 8;             \
    v0 = *(const bf16x8*)(vt + vb_);                                   \
    v1 = *(const bf16x8*)(vt + vb_ + (size_t)16 * 2048);               \
    v2 = *(const bf16x8*)(vt + vb_ + (size_t)32 * 2048);               \
    v3 = *(const bf16x8*)(vt + vb_ + (size_t)48 * 2048);               \
  } while (0)

  // QK^T from LDS K (wave w's 32-key tile = buffer rows w*32..w*32+31).
#define QKM(KT)                                                        \
  do {                                                                 \
    const int j0_ = (KT) * 32;                                         \
    const int rA_ = w * 32 + lr, rB_ = rA_ + 16;                       \
    const __bf16* Kb_ = (const __bf16*)BUF;                            \
    const bf16x8 fk0 = *(const bf16x8*)(Kb_ + KOFF(rA_, lg));          \
    const bf16x8 fk1 = *(const bf16x8*)(Kb_ + KOFF(rA_, 4 + lg));      \
    const bf16x8 fl0 = *(const bf16x8*)(Kb_ + 8192 + KOFF(rA_, lg));   \
    const bf16x8 fl1 = *(const bf16x8*)(Kb_ + 8192 + KOFF(rA_, 4 + lg)); \
    const bf16x8 gk0 = *(const bf16x8*)(Kb_ + KOFF(rB_, lg));          \
    const bf16x8 gk1 = *(const bf16x8*)(Kb_ + KOFF(rB_, 4 + lg));      \
    const bf16x8 gl0 = *(const bf16x8*)(Kb_ + 8192 + KOFF(rB_, lg));   \
    const bf16x8 gl1 = *(const bf16x8*)(Kb_ + 8192 + KOFF(rB_, 4 + lg)); \
    const f32x4 z_ = {0.f, 0.f, 0.f, 0.f};                             \
    {                                                                  \
      f32x4 c0_ = MFMA16(fk1, fqh1, MFMA16(fk0, fqh0, z_));            \
      f32x4 c1_ = MFMA16(fk1, fql1, MFMA16(fk0, fql0, z_));            \
      f32x4 c2_ = MFMA16(fl1, fqh1, MFMA16(fl0, fqh0, z_));            \
      sa = c0_ + c1_ + c2_;                                            \
    }                                                                  \
    sb = (f32x4){NEG, NEG, NEG, NEG};                                  \
    if ((j0_ + 16) <= (q0 + 15)) {                                     \
      f32x4 c0_ = MFMA16(gk1, fqh1, MFMA16(gk0, fqh0, z_));            \
      f32x4 c1_ = MFMA16(gk1, fql1, MFMA16(gk0, fql0, z_));            \
      f32x4 c2_ = MFMA16(gl1, fqh1, MFMA16(gl0, fqh0, z_));            \
      sb = c0_ + c1_ + c2_;                                            \
    }                                                                  \
    _Pragma("unroll") for (int i = 0; i < 4; ++i) {                    \
      if (j0_ + lg * 4 + i > q0 + lr) sa[i] = NEG;                     \
      if (j0_ + 16 + lg * 4 + i > q0 + lr) sb[i] = NEG;                \
    }                                                                  \
  } while (0)

#define SPV()                                                          \
  do {                                                                 \
    float t_ = fmaxf(fmaxf(fmaxf(sa[0], sa[1]), fmaxf(sa[2], sa[3])),  \
                     fmaxf(fmaxf(sb[0], sb[1]), fmaxf(sb[2], sb[3]))); \
    t_ = fmaxf(t_, __shfl_xor(t_, 16, 64));                            \
    t_ = fmaxf(t_, __shfl_xor(t_, 32, 64));                            \
    const float mn_ = fmaxf(m_s, t_);                                  \
    const float sc_ = __expf(m_s - mn_);                               \
    m_s = mn_;                                                         \
    const float pa0_ = __expf(sa[0] - mn_), pa1_ = __expf(sa[1] - mn_);\
    const float pa2_ = __expf(sa[2] - mn_), pa3_ = __expf(sa[3] - mn_);\
    const float pb0_ = __expf(sb[0] - mn_), pb1_ = __expf(sb[1] - mn_);\
    const float pb2_ = __expf(sb[2] - mn_), pb3_ = __expf(sb[3] - mn_);\
    su_s = su_s * sc_ + ((pa0_ + pa1_) + (pa2_ + pa3_)) +              \
           ((pb0_ + pb1_) + (pb2_ + pb3_));                            \
    _Pragma("unroll") for (int i = 0; i < 4; ++i) {                    \
      const float scr_ = __shfl(sc_, lg * 4 + i, 64);                  \
      o0[i] *= scr_; o1[i] *= scr_; o2[i] *= scr_; o3[i] *= scr_;      \
    }                                                                  \
    const unsigned x0_ = pk2(pa0_, pa1_), x1_ = pk2(pa2_, pa3_);       \
    const unsigned y0_ = pk2(pb0_, pb1_), y1_ = pk2(pb2_, pb3_);       \
    const bool e_ = (lg & 1) != 0;                                     \
    const unsigned s0_ = e_ ? x0_ : y0_, s1_ = e_ ? x1_ : y1_;         \
    const unsigned r0_ = __shfl_xor(s0_, 16, 64);                      \
    const unsigned r1_ = __shfl_xor(s1_, 16, 64);                      \
    unsigned z0_ = e_ ? r0_ : x0_;                                     \
    unsigned z1_ = e_ ? r1_ : x1_;                                     \
    unsigned z2_ = e_ ? y0_ : r0_;                                     \
    unsigned z3_ = e_ ? y1_ : r1_;                                     \
    const unsigned u0_ = __shfl_xor(z0_, 48, 64);                      \
    const unsigned u1_ = __shfl_xor(z1_, 48, 64);                      \
    const unsigned u2_ = __shfl_xor(z2_, 48, 64);                      \
    const unsigned u3_ = __shfl_xor(z3_, 48, 64);                      \
    const bool sw_ = (lg == 1) || (lg == 2);                           \
    z0_ = sw_ ? u0_ : z0_; z1_ = sw_ ? u1_ : z1_;                      \
    z2_ = sw_ ? u2_ : z2_; z3_ = sw_ ? u3_ : z3_;                      \
    union { unsigned u[4]; bf16x8 v; } pfu_;                           \
    pfu_.u[0] = z0_; pfu_.u[1] = z1_;                                  \
    pfu_.u[2] = z2_; pfu_.u[3] = z3_;                                  \
    const bf16x8 pf_ = pfu_.v;                                         \
    o0 = MFMA16(pf_, v0, o0);                                          \
    o1 = MFMA16(pf_, v1, o1);                                          \
    o2 = MFMA16(pf_, v2, o2);                                          \
    o3 = MFMA16(pf_, v3, o3);                                          \
  } while (0)

#pragma unroll 1
  for (int sup = 0; sup < nsup; ++sup) {
    if (sup) __syncthreads();        // waves done reading previous K tiles
    STAGE(sup);                      // DMA kh+kl (32KB) -> BUF
    const int kt = sup * 4 + w;      // this wave's tile in the superstep
    const bool act = kt < nkt;       // wave-uniform
    if (act) LDV(kt);                // V in regs; hidden under the drain
    __syncthreads();                 // vmcnt(0) drain: DMA + V complete
    if (act) {
      QKM(kt);                       // K frags from LDS (swizzled ds_read)
      SPV();
    }
  }
#undef KOFF
#undef STAGE
#undef LDV
#undef QKM
#undef SPV

  // per-output-row final running max; full row denom (sum over 4 lg-lanes)
  float m_or[4];
#pragma unroll
  for (int i = 0; i < 4; ++i) m_or[i] = __shfl(m_s, lg * 4 + i, 64);
  float su_row = su_s;
  su_row += __shfl_xor(su_row, 16, 64);
  su_row += __shfl_xor(su_row, 32, 64);

  // ------- LSE merge of the 4 per-wave partials (OB aliases BUF) -------
  float (*OB)[16][68] = (float (*)[16][68])BUF;  // 4*16*68*4 = 17408 B
  if (l < 16) {  // lg==0 lanes cover lr=0..15
    Sm[w][l] = m_s;
    Sl[w][l] = su_row;
  }
  __syncthreads();  // also fences last K reads before BUF reuse
#pragma unroll
  for (int i = 0; i < 4; ++i) {
    const int row = lg * 4 + i;
    float M = fmaxf(fmaxf(Sm[0][row], Sm[1][row]),
                    fmaxf(Sm[2][row], Sm[3][row]));
    const float sc = __expf(m_or[i] - M);  // 0 if this wave was idle
    OB[w][row][lr] = o0[i] * sc;
    OB[w][row][16 + lr] = o1[i] * sc;
    OB[w][row][32 + lr] = o2[i] * sc;
    OB[w][row][48 + lr] = o3[i] * sc;
    if (w == 0 && lr == 0) {
      float denom = 0.f;
#pragma unroll
      for (int w2 = 0; w2 < 4; ++w2)
        denom += Sl[w2][row] * __expf(Sm[w2][row] - M);
      Dinv[row] = 1.0f / denom;
    }
  }
  __syncthreads();
  const int t2 = threadIdx.x;
#pragma unroll
  for (int k2 = 0; k2 < 4; ++k2) {
    const int e2 = t2 + 256 * k2;
    const int row = e2 >> 6, col = e2 & 63;
    const float s = OB[0][row][col] + OB[1][row][col] + OB[2][row][col] +
                    OB[3][row][col];
    out[((size_t)b * TT + q0 + row) * 64 + col] = s * Dinv[row];
  }
}

// ------------------------------------------------------------------ launch ---
extern "C" void kernel_launch(void* const* d_in, const int* in_sizes, int n_in,
                              void* d_out, int out_size, void* d_ws,
                              size_t ws_size, hipStream_t stream) {
  const float* x = (const float*)d_in[0];
  const float* Wq = (const float*)d_in[1];
  const float* Wk = (const float*)d_in[2];
  const float* Wv = (const float*)d_in[3];
  float* out = (float*)d_out;
  char* ws = (char*)d_ws;

  size_t off = 0;
  __bf16* WC = (__bf16*)(ws + off); off += (size_t)64 * WSLICE_S * 2;  // 655KB
  __bf16* qh = (__bf16*)(ws + off); off += (size_t)NROW * 64 * 2;
  __bf16* ql = (__bf16*)(ws + off); off += (size_t)NROW * 64 * 2;
  __bf16* kh = (__bf16*)(ws + off); off += (size_t)NROW * 64 * 2;
  __bf16* kl = (__bf16*)(ws + off); off += (size_t)NROW * 64 * 2;
  __bf16* vt = (__bf16*)(ws + off); off += (size_t)NROW * 64 * 2;  // ~11.1 MB

  wprep_kernel<<<dim3(32), dim3(256), 0, stream>>>(Wq, Wk, Wv, WC);
  proj_kernel<<<dim3(512), dim3(512), 0, stream>>>(
      x, WC, qh, ql, kh, kl, vt);
  attn_kernel<<<dim3(1024), dim3(256), 0, stream>>>(
      qh, ql, kh, kl, vt, out);
}